// Round 1
// baseline (162.119 us; speedup 1.0000x reference)
//
#include <hip/hip_runtime.h>

// change[i] (i>=1)  = ((g(i-3) - g(i+2)) / 5)^2   with g(k)=f[k] zero-padded
// change[0] = 0
// out[i] = (1 - change[i]/S)^5 * f[i],  S = sum(change)

__device__ __forceinline__ float change_term(const float* __restrict__ f, long long i, long long n) {
    if (i < 1) return 0.0f;
    float a = (i >= 3)      ? f[i - 3] : 0.0f;
    float b = (i + 2 < n)   ? f[i + 2] : 0.0f;
    float d = (a - b) * 0.2f;
    return d * d;
}

__global__ void reduce_change_kernel(const float* __restrict__ f, long long n,
                                     float* __restrict__ sum_out) {
    long long i0 = (long long)blockIdx.x * blockDim.x + threadIdx.x;
    long long stride = (long long)gridDim.x * blockDim.x;
    float acc = 0.0f;
    for (long long i = i0; i < n; i += stride) {
        acc += change_term(f, i, n);
    }
    // wave (64-lane) reduction
    #pragma unroll
    for (int off = 32; off > 0; off >>= 1)
        acc += __shfl_down(acc, off, 64);
    __shared__ float smem[4];  // 256 threads / 64 lanes
    int lane = threadIdx.x & 63;
    int wave = threadIdx.x >> 6;
    if (lane == 0) smem[wave] = acc;
    __syncthreads();
    if (threadIdx.x == 0) {
        float s = smem[0] + smem[1] + smem[2] + smem[3];
        atomicAdd(sum_out, s);
    }
}

__global__ void finalize_kernel(const float* __restrict__ f, long long n,
                                const float* __restrict__ sum_in,
                                float* __restrict__ out) {
    long long i = (long long)blockIdx.x * blockDim.x + threadIdx.x;
    if (i >= n) return;
    float inv = 1.0f / *sum_in;
    float c = change_term(f, i, n) * inv;
    float t = 1.0f - c;
    float t2 = t * t;
    out[i] = t2 * t2 * t * f[i];
}

extern "C" void kernel_launch(void* const* d_in, const int* in_sizes, int n_in,
                              void* d_out, int out_size, void* d_ws, size_t ws_size,
                              hipStream_t stream) {
    const float* f = (const float*)d_in[0];
    float* out = (float*)d_out;
    float* sum_ws = (float*)d_ws;
    long long n = (long long)in_sizes[0];

    hipMemsetAsync(d_ws, 0, sizeof(float), stream);

    const int block = 256;
    const int rgrid = 2048;  // grid-stride; 2048 atomics total
    reduce_change_kernel<<<rgrid, block, 0, stream>>>(f, n, sum_ws);

    long long fgrid = (n + block - 1) / block;
    finalize_kernel<<<(int)fgrid, block, 0, stream>>>(f, n, sum_ws, out);
}